// Round 6
// baseline (5250.030 us; speedup 1.0000x reference)
//
#include <hip/hip_runtime.h>

#define TLEN 256
#define DD 8
#define HH 128
#define NT 1024

typedef __attribute__((ext_vector_type(8))) _Float16 half8;
typedef __attribute__((ext_vector_type(4))) float f32x4;

#define LOSCALE 65536.0f
#define LOINV   (1.0f/65536.0f)

static __device__ __forceinline__ float tanh_fast(float x){
  float cx = fminf(fmaxf(x, -9.01f), 9.01f);
  float e = __builtin_amdgcn_exp2f(cx * 2.885390081777927f); // exp(2x)
  return 1.0f - 2.0f * __builtin_amdgcn_rcpf(e + 1.0f);
}

// ---- pack W2 into MFMA fragment order: hi (unscaled) + lo (x65536), fp16.
// frag f = C16*4 + kt (C16 = 16-col block 0..63); lane l holds
// W2[kt*32+(l>>4)*8+j][C16*16+(l&15)], j=0..7
__global__ void pack_w2_kernel(const float* __restrict__ W2, half8* __restrict__ ws){
  int gid = blockIdx.x * 256 + threadIdx.x;
  int l = gid & 63;
  int f = gid >> 6;                           // 0..255
  int kt = f & 3, c16 = f >> 2;
  int col = c16*16 + (l & 15);
  int kb  = kt*32 + (l >> 4)*8;
  half8 vh, vl;
  #pragma unroll
  for (int j = 0; j < 8; j++){
    float v = W2[(kb + j)*1024 + col];
    _Float16 h = (_Float16)v;
    vh[j] = h;
    vl[j] = (_Float16)((v - (float)h) * LOSCALE);
  }
  ws[f*64 + l] = vh;            // hi region: frags [0,256)
  ws[(256 + f)*64 + l] = vl;    // lo region
}

// One block = 16 batch rows, 16 waves (4 waves/SIMD).
// Waves 0-7: G1/G2 (wave q owns h-cols [16q,16q+16)). All 16 waves: G3 c-split
// (wave q owns G3^T rows [64q, 64q+64) = 4 subtiles j). Waves 8-15 do the
// out-write during the G1 phase.
__global__ __launch_bounds__(NT, 4) void ncde_kernel(
    const float* __restrict__ x, const float* __restrict__ Win, const float* __restrict__ bin,
    const float* __restrict__ W0, const float* __restrict__ b0v, const float* __restrict__ W1,
    const float* __restrict__ b1v, const float* __restrict__ W2, const float* __restrict__ b2v,
    const half8* __restrict__ wsw2, float* __restrict__ out)
{
  __shared__ half8 w0fh[2048], w0fl[2048];   // 64 KB  W0 hi / lo(x65536)
  __shared__ half8 w1fh[2048], w1fl[2048];   // 64 KB
  __shared__ unsigned short act[6*2048];     // 24 KB: zh,zl,h1h,h1l,h2h,h2l @ buf*4096
  __shared__ float b2lds[1024];              // 4 KB

  const int t    = threadIdx.x;
  const int lane = t & 63;
  const int q    = t >> 6;        // wave 0..15
  const int lg   = lane >> 4;
  const int ln   = lane & 15;
  const int b0blk = blockIdx.x * 16;
  const int dbase = (lg & 1) * 4;
  char* const actc = (char*)act;

  // ---- one-time: W0/W1 -> LDS hi/lo B-fragments
  for (int s = t; s < 4096; s += NT){
    int which = s >> 11;
    int s2 = s & 2047;
    int la = s2 & 63;
    int nt = (s2 >> 6) & 7;
    int kt = s2 >> 9;
    const float* Wsrc = which ? W1 : W0;
    int kb  = kt*32 + (la >> 4)*8;
    int col = nt*16 + (la & 15);
    half8 vh, vl;
    #pragma unroll
    for (int j = 0; j < 8; j++){
      float v = Wsrc[(kb + j)*HH + col];
      _Float16 h = (_Float16)v;
      vh[j] = h;
      vl[j] = (_Float16)((v - (float)h)*LOSCALE);
    }
    if (which){ w1fh[s2] = vh; w1fl[s2] = vl; } else { w0fh[s2] = vh; w0fl[s2] = vl; }
  }
  for (int s = t; s < 1024; s += NT) b2lds[s] = b2v[s];

  const half8* wsL = wsw2 + 256*64;

  const float b0r = b0v[(q & 7)*16 + ln];
  const float w0L = W0[128*HH + (q & 7)*16 + ln];
  const float b1r = b1v[(q & 7)*16 + ln];

  // precomputed LDS byte offsets
  unsigned ard[4];
  #pragma unroll
  for (int kt = 0; kt < 4; kt++)
    ard[kt] = (unsigned)ln*256u + (((unsigned)(kt*64 + lg*16)) ^ (((unsigned)(ln & 7)) << 4));
  unsigned sst[4];
  #pragma unroll
  for (int r = 0; r < 4; r++){
    int row = lg*4 + r;
    sst[r] = (unsigned)row*256u + ((((unsigned)((q & 7)*16 + ln))*2u) ^ (((unsigned)(row & 7)) << 4));
  }
  unsigned zst[4];
  #pragma unroll
  for (int j = 0; j < 4; j++){
    int h = q*8 + j*2 + (lg >> 1);
    zst[j] = (unsigned)ln*256u + (((unsigned)h*2u) ^ (((unsigned)(ln & 7)) << 4));
  }

  const float* xb = x + (size_t)(b0blk + ln)*(TLEN*DD) + dbase;
  f32x4 xprev = *(const f32x4*)xb;

  // ---- z0 = x[:,0,:] @ Win + bin (exact fp32)
  for (int o = t; o < 2048; o += NT){
    int br = o >> 7, h = o & 127;
    float acc = bin[h];
    const float* xr = x + (size_t)(b0blk + br)*(TLEN*DD);
    #pragma unroll
    for (int d = 0; d < DD; d++) acc += xr[d] * Win[d*HH + h];
    unsigned byte = (unsigned)br*256u + (((unsigned)h*2u) ^ (((unsigned)(br & 7)) << 4));
    _Float16 hv = (_Float16)acc;
    *(_Float16*)(actc + byte)        = hv;
    *(_Float16*)(actc + byte + 4096) = (_Float16)(acc - (float)hv);
  }
  __syncthreads();

  // z accumulators: zreg[j] = z[b=ln][h = q*8 + j*2 + (lg>>1)]
  float zreg[4];
  #pragma unroll
  for (int j = 0; j < 4; j++)
    zreg[j] = (float)*(_Float16*)(actc + zst[j])
            + (float)*(_Float16*)(actc + zst[j] + 4096);

  for (int k = 0; k < TLEN - 1; k++){
    float tk = (float)k * (1.0f/255.0f);
    f32x4 xn = *(const f32x4*)(xb + (size_t)(k + 1)*DD);

    if (q < 8){
      // ---- G1: h1 = relu([z,t] @ W0 + b0)
      f32x4 ah = {0,0,0,0}, al = {0,0,0,0}, ac = {0,0,0,0};
      #pragma unroll
      for (int kt = 0; kt < 4; kt++){
        half8 zh_ = *(const half8*)(actc + ard[kt]);
        half8 zl_ = *(const half8*)(actc + ard[kt] + 4096);
        half8 bh = w0fh[(kt*8 + q)*64 + lane];
        half8 bl = w0fl[(kt*8 + q)*64 + lane];
        ah = __builtin_amdgcn_mfma_f32_16x16x32_f16(zh_, bh, ah, 0, 0, 0);
        al = __builtin_amdgcn_mfma_f32_16x16x32_f16(zl_, bh, al, 0, 0, 0);
        ac = __builtin_amdgcn_mfma_f32_16x16x32_f16(zh_, bl, ac, 0, 0, 0);
      }
      float c0 = b0r + tk * w0L;
      #pragma unroll
      for (int r = 0; r < 4; r++){
        float v = fmaxf(ah[r] + al[r] + ac[r]*LOINV + c0, 0.0f);
        _Float16 hv = (_Float16)v;
        *(_Float16*)(actc + sst[r] + 2*4096) = hv;
        *(_Float16*)(actc + sst[r] + 3*4096) = (_Float16)(v - (float)hv);
      }
    } else {
      // ---- out[:,k,:] (z_k is current in zh/zl; overlaps G1)
      #pragma unroll
      for (int i = 0; i < 4; i++){
        int o = (t - 512) + i*512;
        int br = o >> 7, h = o & 127;
        unsigned byte = (unsigned)br*256u + (((unsigned)h*2u) ^ (((unsigned)(br & 7)) << 4));
        float val = (float)*(_Float16*)(actc + byte)
                  + (float)*(_Float16*)(actc + byte + 4096);
        out[(size_t)(b0blk + br)*(TLEN*HH) + (size_t)k*HH + h] = val;
      }
    }
    __syncthreads(); // B1

    if (q < 8){
      // ---- G2: h2 = relu(h1 @ W1 + b1)
      f32x4 ah = {0,0,0,0}, al = {0,0,0,0}, ac = {0,0,0,0};
      #pragma unroll
      for (int kt = 0; kt < 4; kt++){
        half8 zh_ = *(const half8*)(actc + ard[kt] + 2*4096);
        half8 zl_ = *(const half8*)(actc + ard[kt] + 3*4096);
        half8 bh = w1fh[(kt*8 + q)*64 + lane];
        half8 bl = w1fl[(kt*8 + q)*64 + lane];
        ah = __builtin_amdgcn_mfma_f32_16x16x32_f16(zh_, bh, ah, 0, 0, 0);
        al = __builtin_amdgcn_mfma_f32_16x16x32_f16(zl_, bh, al, 0, 0, 0);
        ac = __builtin_amdgcn_mfma_f32_16x16x32_f16(zh_, bl, ac, 0, 0, 0);
      }
      #pragma unroll
      for (int r = 0; r < 4; r++){
        float v = fmaxf(ah[r] + al[r] + ac[r]*LOINV + b1r, 0.0f);
        _Float16 hv = (_Float16)v;
        *(_Float16*)(actc + sst[r] + 4*4096) = hv;
        *(_Float16*)(actc + sst[r] + 5*4096) = (_Float16)(v - (float)hv);
      }
    }
    // prefetch W2 frags for j=0 (global; overlaps barrier wait)
    half8 wh[4], wlo[4];
    #pragma unroll
    for (int kt = 0; kt < 4; kt++){
      wh[kt]  = wsw2[(q*16 + kt)*64 + lane];
      wlo[kt] = wsL [(q*16 + kt)*64 + lane];
    }
    __syncthreads(); // B2

    // ---- G3 transposed: rows c = q*64 + j*16 + lg*4 + r, cols b = ln
    f32x4 dxr = xn - xprev; xprev = xn;
    float sacc[4];
    __builtin_amdgcn_s_setprio(1);
    #pragma unroll
    for (int j = 0; j < 4; j++){
      f32x4 hh = {0,0,0,0}, hl = {0,0,0,0}, hc = {0,0,0,0};
      #pragma unroll
      for (int kt = 0; kt < 4; kt++){
        half8 ah_ = *(const half8*)(actc + ard[kt] + 4*4096);
        half8 al_ = *(const half8*)(actc + ard[kt] + 5*4096);
        hh = __builtin_amdgcn_mfma_f32_16x16x32_f16(wh[kt],  ah_, hh, 0, 0, 0);
        hl = __builtin_amdgcn_mfma_f32_16x16x32_f16(wh[kt],  al_, hl, 0, 0, 0);
        hc = __builtin_amdgcn_mfma_f32_16x16x32_f16(wlo[kt], ah_, hc, 0, 0, 0);
      }
      if (j < 3){
        #pragma unroll
        for (int kt = 0; kt < 4; kt++){
          wh[kt]  = wsw2[(q*16 + (j + 1)*4 + kt)*64 + lane];
          wlo[kt] = wsL [(q*16 + (j + 1)*4 + kt)*64 + lane];
        }
      }
      f32x4 b2q = *(const f32x4*)&b2lds[q*64 + j*16 + lg*4];
      float s = 0.0f;
      #pragma unroll
      for (int r = 0; r < 4; r++)
        s += tanh_fast(hh[r] + hl[r] + hc[r]*LOINV + b2q[r]) * dxr[r];
      sacc[j] = s;
    }
    __builtin_amdgcn_s_setprio(0);

    // batched cross-half combine + z update
    #pragma unroll
    for (int j = 0; j < 4; j++){
      sacc[j] += __shfl_xor(sacc[j], 16, 64);
      zreg[j] += sacc[j];
    }
    if ((lg & 1) == 0){
      #pragma unroll
      for (int j = 0; j < 4; j++){
        float v = zreg[j];
        _Float16 hv = (_Float16)v;
        *(_Float16*)(actc + zst[j])        = hv;
        *(_Float16*)(actc + zst[j] + 4096) = (_Float16)(v - (float)hv);
      }
    }
    __syncthreads(); // B3
  }

  // ---- final out[:,T-1,:]
  for (int o = t; o < 2048; o += NT){
    int br = o >> 7, h = o & 127;
    unsigned byte = (unsigned)br*256u + (((unsigned)h*2u) ^ (((unsigned)(br & 7)) << 4));
    out[(size_t)(b0blk + br)*(TLEN*HH) + (size_t)(TLEN - 1)*HH + h] =
        (float)*(_Float16*)(actc + byte) + (float)*(_Float16*)(actc + byte + 4096);
  }
}

extern "C" void kernel_launch(void* const* d_in, const int* in_sizes, int n_in,
                              void* d_out, int out_size, void* d_ws, size_t ws_size,
                              hipStream_t stream) {
  const float* x   = (const float*)d_in[0];
  const float* Win = (const float*)d_in[1];
  const float* bin = (const float*)d_in[2];
  const float* W0  = (const float*)d_in[3];
  const float* b0  = (const float*)d_in[4];
  const float* W1  = (const float*)d_in[5];
  const float* b1  = (const float*)d_in[6];
  const float* W2  = (const float*)d_in[7];
  const float* b2  = (const float*)d_in[8];
  float* out = (float*)d_out;
  half8* wsw2 = (half8*)d_ws;   // 512 KB: 256 hi frags + 256 lo frags

  pack_w2_kernel<<<dim3(64), dim3(256), 0, stream>>>(W2, wsw2);
  ncde_kernel<<<dim3(64), dim3(NT), 0, stream>>>(
      x, Win, bin, W0, b0, W1, b1, W2, b2, wsw2, out);
}

// Round 7
// 2274.568 us; speedup vs baseline: 2.3081x; 2.3081x over previous
//
#include <hip/hip_runtime.h>

#define TLEN 256
#define DD 8
#define HH 128
#define BR 16
#define NTHREADS 512

typedef __attribute__((ext_vector_type(8))) _Float16 half8;
typedef __attribute__((ext_vector_type(4))) float f32x4;

#define LOSCALE 65536.0f
#define LOINV   (1.0f/65536.0f)

static __device__ __forceinline__ float tanh_fast(float x){
  float cx = fminf(fmaxf(x, -9.01f), 9.01f);
  float e = __builtin_amdgcn_exp2f(cx * 2.885390081777927f); // exp(2x)
  return 1.0f - 2.0f * __builtin_amdgcn_rcpf(e + 1.0f);
}

static __device__ __forceinline__ void split_store(float v, unsigned short* hiA, unsigned short* loA, unsigned byte){
  _Float16 h = (_Float16)v;
  _Float16 l = (_Float16)(v - (float)h);
  *(_Float16*)((char*)hiA + byte) = h;
  *(_Float16*)((char*)loA + byte) = l;
}

// ---- pack W2 into MFMA fragment order: hi (unscaled) + lo (x65536), fp16.
// frag f = (w*8+ct)*4+kt, lane l holds W2[kt*32+(l>>4)*8+j][w*128+ct*16+(l&15)], j=0..7
__global__ void pack_w2_kernel(const float* __restrict__ W2, half8* __restrict__ ws){
  int gid = blockIdx.x * 256 + threadIdx.x;
  int l = gid & 63;
  int f = gid >> 6;                           // 0..255
  int kt = f & 3, ct = (f >> 2) & 7, w = f >> 5;
  int col = w*128 + ct*16 + (l & 15);
  int kb  = kt*32 + (l >> 4)*8;
  half8 vh, vl;
  #pragma unroll
  for (int j = 0; j < 8; j++){
    float v = W2[(kb + j)*1024 + col];
    _Float16 h = (_Float16)v;
    vh[j] = h;
    vl[j] = (_Float16)((v - (float)h) * LOSCALE);
  }
  ws[f*64 + l] = vh;            // hi region: frags [0,256)
  ws[(256 + f)*64 + l] = vl;    // lo region
}

// One block = 16 batch rows for the whole T recurrence. 8 waves, EXACTLY 2 waves/EU
// so the allocator has the full 256-VGPR budget and keeps W2-hi register-resident.
__global__ __launch_bounds__(NTHREADS)
__attribute__((amdgpu_waves_per_eu(2, 2)))
void ncde_kernel(
    const float* __restrict__ x, const float* __restrict__ Win, const float* __restrict__ bin,
    const float* __restrict__ W0, const float* __restrict__ b0v, const float* __restrict__ W1,
    const float* __restrict__ b1v, const float* __restrict__ W2, const float* __restrict__ b2v,
    const half8* __restrict__ wsw2, float* __restrict__ out)
{
  __shared__ half8 w0fh[2048], w0fl[2048];   // 32+32 KB  W0 hi / lo(x65536)
  __shared__ half8 w1fh[2048], w1fl[2048];   // 32+32 KB
  __shared__ unsigned short zhh[2048], zhl[2048];  // fp16 z hi/lo, XOR-swizzled
  __shared__ unsigned short h1h[2048], h1l[2048];
  __shared__ unsigned short h2h[2048], h2l[2048];  // 6 x 4 KB
  __shared__ f32x4 b2lds4[256];              // 4 KB

  const int t    = threadIdx.x;
  const int lane = t & 63;
  const int w    = t >> 6;        // wave 0..7
  const int lg   = lane >> 4;     // lane group 0..3
  const int ln   = lane & 15;
  const int b0blk = blockIdx.x * BR;
  const int dbase = (lg & 1) * 4;

  // ---- one-time: W0/W1 -> LDS hi/lo B-fragments
  for (int s = t; s < 4096; s += NTHREADS){
    int which = s >> 11;
    int s2 = s & 2047;
    int la = s2 & 63;
    int nt = (s2 >> 6) & 7;
    int kt = s2 >> 9;
    const float* Wsrc = which ? W1 : W0;
    int kb  = kt*32 + (la >> 4)*8;
    int col = nt*16 + (la & 15);
    half8 vh, vl;
    #pragma unroll
    for (int j = 0; j < 8; j++){
      float v = Wsrc[(kb + j)*HH + col];
      _Float16 h = (_Float16)v;
      vh[j] = h;
      vl[j] = (_Float16)((v - (float)h)*LOSCALE);
    }
    if (which){ w1fh[s2] = vh; w1fl[s2] = vl; } else { w0fh[s2] = vh; w0fl[s2] = vl; }
  }
  for (int s = t; s < 1024; s += NTHREADS) ((float*)b2lds4)[s] = b2v[s];

  // ---- one-time: W2 hi fragments -> registers (128 VGPRs, must stay resident)
  half8 w2f[8][4];
  #pragma unroll
  for (int ct = 0; ct < 8; ct++)
    #pragma unroll
    for (int kt = 0; kt < 4; kt++)
      w2f[ct][kt] = wsw2[((w*8 + ct)*4 + kt)*64 + lane];
  const half8* wsL = wsw2 + 256*64;

  const float b0r = b0v[w*16 + ln];
  const float w0L = W0[128*HH + w*16 + ln];   // time-channel row (exact fp32)
  const float b1r = b1v[w*16 + ln];

  // xprev: this lane's 4 dx-channels of batch row b=ln
  const float* xb = x + (size_t)(b0blk + ln)*(TLEN*DD) + dbase;
  f32x4 xprev = *(const f32x4*)xb;

  // ---- z0 = x[:,0,:] @ Win + bin (exact fp32), stored as fp16 hi/lo
  for (int o = t; o < BR*HH; o += NTHREADS){
    int br = o >> 7, h = o & 127;
    float acc = bin[h];
    const float* xr = x + (size_t)(b0blk + br)*(TLEN*DD);
    #pragma unroll
    for (int d = 0; d < DD; d++) acc += xr[d] * Win[d*HH + h];
    unsigned byte = (unsigned)br*256u + (((unsigned)h*2u) ^ (((unsigned)(br & 7)) << 4));
    split_store(acc, zhh, zhl, byte);
  }
  __syncthreads();

  // z accumulator: zreg[ct] = z[b=ln][h = w*16 + ct*2 + (lg>>1)] (duplicated across lg-pairs)
  float zreg[8];
  #pragma unroll
  for (int ct = 0; ct < 8; ct++){
    int h = w*16 + ct*2 + (lg >> 1);
    unsigned byte = (unsigned)ln*256u + (((unsigned)h*2u) ^ (((unsigned)(ln & 7)) << 4));
    zreg[ct] = (float)*(_Float16*)((char*)zhh + byte) + (float)*(_Float16*)((char*)zhl + byte);
  }

  // out[:,0,:] + 32-bit per-thread row offsets (base pointer stepped uniformly)
  unsigned orow[4]; unsigned olds[4];
  #pragma unroll
  for (int i = 0; i < 4; i++){
    int o = t + i*NTHREADS;
    int br = o >> 7, h = o & 127;
    orow[i] = (unsigned)(b0blk + br)*(TLEN*HH) + (unsigned)h;
    olds[i] = (unsigned)br*256u + (((unsigned)h*2u) ^ (((unsigned)(br & 7)) << 4));
    out[orow[i]] = (float)*(_Float16*)((char*)zhh + olds[i])
                 + (float)*(_Float16*)((char*)zhl + olds[i]);
  }

  const float inv = 1.0f / 255.0f;

  for (int k = 0; k < TLEN - 1; k++){
    float tk = (float)k * inv;

    f32x4 xn = *(const f32x4*)(xb + (size_t)(k + 1)*DD);

    // ---- GEMM1: h1 = relu([z,t] @ W0 + b0)  (3 parallel 4-deep MFMA chains)
    f32x4 acch = {0.f,0.f,0.f,0.f}, accl = {0.f,0.f,0.f,0.f}, acc2 = {0.f,0.f,0.f,0.f};
    #pragma unroll
    for (int kt = 0; kt < 4; kt++){
      unsigned byte = (unsigned)ln*256u + ((((unsigned)(kt*4 + lg))*16u) ^ (((unsigned)(ln & 7)) << 4));
      half8 ahi = *(const half8*)((const char*)zhh + byte);
      half8 alo = *(const half8*)((const char*)zhl + byte);
      half8 bh = w0fh[(kt*8 + w)*64 + lane];
      half8 bl = w0fl[(kt*8 + w)*64 + lane];
      acch = __builtin_amdgcn_mfma_f32_16x16x32_f16(ahi, bh, acch, 0, 0, 0);
      accl = __builtin_amdgcn_mfma_f32_16x16x32_f16(alo, bh, accl, 0, 0, 0);
      acc2 = __builtin_amdgcn_mfma_f32_16x16x32_f16(ahi, bl, acc2, 0, 0, 0);
    }
    {
      float c0 = b0r + tk * w0L;
      #pragma unroll
      for (int r = 0; r < 4; r++){
        float v = fmaxf(acch[r] + accl[r] + acc2[r]*LOINV + c0, 0.0f);
        int row = lg*4 + r;
        unsigned byte = (unsigned)row*256u + ((((unsigned)(w*16 + ln))*2u) ^ (((unsigned)(row & 7)) << 4));
        split_store(v, h1h, h1l, byte);
      }
    }
    __syncthreads(); // B1

    // ---- GEMM2: h2 = relu(h1 @ W1 + b1)
    acch = (f32x4){0.f,0.f,0.f,0.f}; accl = (f32x4){0.f,0.f,0.f,0.f}; acc2 = (f32x4){0.f,0.f,0.f,0.f};
    #pragma unroll
    for (int kt = 0; kt < 4; kt++){
      unsigned byte = (unsigned)ln*256u + ((((unsigned)(kt*4 + lg))*16u) ^ (((unsigned)(ln & 7)) << 4));
      half8 ahi = *(const half8*)((const char*)h1h + byte);
      half8 alo = *(const half8*)((const char*)h1l + byte);
      half8 bh = w1fh[(kt*8 + w)*64 + lane];
      half8 bl = w1fl[(kt*8 + w)*64 + lane];
      acch = __builtin_amdgcn_mfma_f32_16x16x32_f16(ahi, bh, acch, 0, 0, 0);
      accl = __builtin_amdgcn_mfma_f32_16x16x32_f16(alo, bh, accl, 0, 0, 0);
      acc2 = __builtin_amdgcn_mfma_f32_16x16x32_f16(ahi, bl, acc2, 0, 0, 0);
    }
    #pragma unroll
    for (int r = 0; r < 4; r++){
      float v = fmaxf(acch[r] + accl[r] + acc2[r]*LOINV + b1r, 0.0f);
      int row = lg*4 + r;
      unsigned byte = (unsigned)row*256u + ((((unsigned)(w*16 + ln))*2u) ^ (((unsigned)(row & 7)) << 4));
      split_store(v, h2h, h2l, byte);
    }
    // prefetch ct=0 W2-lo frags (global; independent of LDS barrier)
    half8 wl[4];
    #pragma unroll
    for (int kt = 0; kt < 4; kt++) wl[kt] = wsL[((w*8 + 0)*4 + kt)*64 + lane];
    __syncthreads(); // B2

    // ---- GEMM3 transposed: G3^T = W2^T (A, regs) x h2^T (B, LDS — same read as A-frag)
    half8 ahh[4], ahl[4];
    #pragma unroll
    for (int kt = 0; kt < 4; kt++){
      unsigned byte = (unsigned)ln*256u + ((((unsigned)(kt*4 + lg))*16u) ^ (((unsigned)(ln & 7)) << 4));
      ahh[kt] = *(const half8*)((const char*)h2h + byte);
      ahl[kt] = *(const half8*)((const char*)h2l + byte);
    }
    f32x4 dxr = xn - xprev;
    xprev = xn;

    #pragma unroll
    for (int ct = 0; ct < 8; ct++){
      f32x4 b2q = b2lds4[w*32 + ct*4 + lg];  // broadcast within 16 lanes, conflict-free
      f32x4 a3h = {0.f,0.f,0.f,0.f}, a3l = {0.f,0.f,0.f,0.f}, a3c = {0.f,0.f,0.f,0.f};
      #pragma unroll
      for (int kt = 0; kt < 4; kt++)
        a3h = __builtin_amdgcn_mfma_f32_16x16x32_f16(w2f[ct][kt], ahh[kt], a3h, 0, 0, 0);
      #pragma unroll
      for (int kt = 0; kt < 4; kt++)
        a3l = __builtin_amdgcn_mfma_f32_16x16x32_f16(w2f[ct][kt], ahl[kt], a3l, 0, 0, 0);
      #pragma unroll
      for (int kt = 0; kt < 4; kt++)
        a3c = __builtin_amdgcn_mfma_f32_16x16x32_f16(wl[kt], ahh[kt], a3c, 0, 0, 0);
      // issue next ct's W2-lo loads (covered by epilogue + next ct's MFMAs)
      if (ct < 7){
        #pragma unroll
        for (int kt = 0; kt < 4; kt++) wl[kt] = wsL[((w*8 + ct + 1)*4 + kt)*64 + lane];
      }
      // lane holds c = w*128 + ct*16 + lg*4 + r  (h = w*16+ct*2+(lg>>1), d = dbase + r)
      float s = 0.0f;
      #pragma unroll
      for (int r = 0; r < 4; r++){
        float val = tanh_fast(a3h[r] + a3l[r] + a3c[r]*LOINV + b2q[r]);
        s += val * dxr[r];
      }
      s += __shfl_xor(s, 16, 64);   // combine the two d-halves (lg pair)
      zreg[ct] += s;
    }

    // z writeback: lanes with even lg own distinct (b,h)
    if ((lg & 1) == 0){
      #pragma unroll
      for (int ct = 0; ct < 8; ct++){
        int h = w*16 + ct*2 + (lg >> 1);
        unsigned byte = (unsigned)ln*256u + (((unsigned)h*2u) ^ (((unsigned)(ln & 7)) << 4));
        split_store(zreg[ct], zhh, zhl, byte);
      }
    }
    __syncthreads(); // B3

    // out[:,k+1,:] — coalesced, reconstructed fp32 = hi + lo
    {
      float* outk = out + (size_t)(k + 1)*HH;
      #pragma unroll
      for (int i = 0; i < 4; i++)
        outk[orow[i]] = (float)*(_Float16*)((char*)zhh + olds[i])
                      + (float)*(_Float16*)((char*)zhl + olds[i]);
    }
  }
}

extern "C" void kernel_launch(void* const* d_in, const int* in_sizes, int n_in,
                              void* d_out, int out_size, void* d_ws, size_t ws_size,
                              hipStream_t stream) {
  const float* x   = (const float*)d_in[0];
  const float* Win = (const float*)d_in[1];
  const float* bin = (const float*)d_in[2];
  const float* W0  = (const float*)d_in[3];
  const float* b0  = (const float*)d_in[4];
  const float* W1  = (const float*)d_in[5];
  const float* b1  = (const float*)d_in[6];
  const float* W2  = (const float*)d_in[7];
  const float* b2  = (const float*)d_in[8];
  float* out = (float*)d_out;
  half8* wsw2 = (half8*)d_ws;   // 512 KB: 256 hi frags + 256 lo frags

  pack_w2_kernel<<<dim3(64), dim3(256), 0, stream>>>(W2, wsw2);
  ncde_kernel<<<dim3(1024 / BR), dim3(NTHREADS), 0, stream>>>(
      x, Win, bin, W0, b0, W1, b1, W2, b2, wsw2, out);
}